// Round 13
// baseline (704.585 us; speedup 1.0000x reference)
//
#include <hip/hip_runtime.h>

typedef unsigned short ushort_t;
typedef __attribute__((ext_vector_type(4))) unsigned short u16x4;
typedef __attribute__((ext_vector_type(8))) unsigned short u16x8;
typedef __attribute__((ext_vector_type(2))) unsigned short u16x2;
typedef __attribute__((ext_vector_type(4))) float f32x4;
typedef __attribute__((ext_vector_type(8))) __bf16 bf16x8;

constexpr int N_ = 768;
constexpr int NN = N_ * N_;   // 589824
constexpr int C  = 128;

__device__ __forceinline__ unsigned short f2bf(float f) {
  union { float f; unsigned int u; } v; v.f = f;
  unsigned int r = v.u + 0x7fffu + ((v.u >> 16) & 1u);
  return (unsigned short)(r >> 16);
}
__device__ __forceinline__ float bf2f(unsigned short u) {
  union { unsigned int i; float f; } v; v.i = ((unsigned int)u) << 16;
  return v.f;
}
// sigmoid with hardware reciprocal (1 op vs ~8-op exact divide); ~2^-22 rel err
__device__ __forceinline__ float sigm(float x) {
  return __builtin_amdgcn_rcpf(1.f + __expf(-x));
}

__device__ __forceinline__ void gload16(const void* g, void* l) {
  __builtin_amdgcn_global_load_lds(
      (const __attribute__((address_space(1))) unsigned int*)g,
      (__attribute__((address_space(3))) unsigned int*)l, 16, 0, 0);
}

// ---------------- K1: LayerNorm(z) -> zn bf16 (ij,c) ----------------
__global__ __launch_bounds__(256) void k1_ln(const float* __restrict__ z,
                                             const float* __restrict__ w,
                                             const float* __restrict__ b,
                                             ushort_t* __restrict__ zn) {
  int row  = blockIdx.x * 4 + (threadIdx.x >> 6);
  int lane = threadIdx.x & 63;
  const float* src = z + (size_t)row * C;
  float2 v = *(const float2*)(src + lane * 2);
  float sm = v.x + v.y;
#pragma unroll
  for (int m = 1; m < 64; m <<= 1) sm += __shfl_xor(sm, m);
  float mean = sm * (1.f / 128.f);
  float d0 = v.x - mean, d1 = v.y - mean;
  float sq = d0 * d0 + d1 * d1;
#pragma unroll
  for (int m = 1; m < 64; m <<= 1) sq += __shfl_xor(sq, m);
  float rstd = rsqrtf(sq * (1.f / 128.f) + 1e-5f);
  float2 wv = *(const float2*)(w + lane * 2);
  float2 bv = *(const float2*)(b + lane * 2);
  u16x2 o; o.x = f2bf(d0 * rstd * wv.x + bv.x); o.y = f2bf(d1 * rstd * wv.y + bv.y);
  *(u16x2*)(zn + (size_t)row * C + lane * 2) = o;
}

// ---------------- K0: weights fp32 -> bf16 (zwb + Wall=[Wp;Wg;Wgate]) ----------------
__global__ void k0_cvt(const float* __restrict__ zw, const float* __restrict__ Wp,
                       const float* __restrict__ Wg, const float* __restrict__ Wgate,
                       ushort_t* __restrict__ zwb, ushort_t* __restrict__ Wall) {
  int i = blockIdx.x * 256 + threadIdx.x;
  if (i < 16384) zwb[i] = f2bf(zw[i]);
  if (i < 81920) {
    float v = (i < 32768) ? Wp[i] : (i < 65536 ? Wg[i - 32768] : Wgate[i - 65536]);
    Wall[i] = f2bf(v);
  }
}

// ---------------- K2: a/b projections only, dual-W-buffer loop ----------------
// Wall rows: p [0,256), g [256,512). (gate rows 512+ consumed by k4 now.)
// LDS 64K: zn 32K @0 (dead after afr hoist; epi 16K overlays @0) | WB0 16K | WB1 16K.
constexpr int K2_ZN  = 0;
constexpr int K2_WB0 = 32768;
constexpr int K2_WB1 = 49152;
__global__ __launch_bounds__(256, 2) void k2_proj(
    const ushort_t* __restrict__ zn, const ushort_t* __restrict__ Wall,
    const float* __restrict__ bp, const float* __restrict__ bg,
    const float* __restrict__ mask,
    ushort_t* __restrict__ a_t, ushort_t* __restrict__ b_t) {
  __shared__ __align__(16) char smem[65536];
  int ij0 = blockIdx.x * 128;
  int t = threadIdx.x, lane = t & 63, wid = t >> 6;
  int rl = lane & 15, gq = lane >> 4;

  auto stage_wb = [&](int wrowbase, int wboff) {
#pragma unroll
    for (int pass = 0; pass < 4; ++pass) {
      int idx = pass * 256 + t;
      int row = idx >> 4, slot = idx & 15;
      int gcol = (slot * 16) ^ ((row & 7) << 4);
      gload16((const char*)Wall + (size_t)(wrowbase + row) * 256 + gcol,
              smem + wboff + idx * 16);
    }
  };

  // prologue: stage zn tile (pre-swizzled source) + first p/g chunk pair
  {
    const char* base = (const char*)(zn + (size_t)ij0 * C);
#pragma unroll
    for (int iss = 0; iss < 8; ++iss) {
      int idx = iss * 256 + t;
      int row = idx >> 4, slot = idx & 15;
      int gcol = (slot * 16) ^ ((row & 7) << 4);
      gload16(base + row * 256 + gcol, smem + K2_ZN + idx * 16);
    }
  }
  stage_wb(0, K2_WB0);
  stage_wb(256, K2_WB1);
  __syncthreads();

  // hoist A-fragments (this wave's 32 zn rows); zn LDS dead afterwards
  bf16x8 afr[4][2];
#pragma unroll
  for (int kk = 0; kk < 4; ++kk) {
    int kb = kk * 64 + gq * 16;
#pragma unroll
    for (int r = 0; r < 2; ++r) {
      int row = wid * 32 + r * 16 + rl;
      afr[kk][r] = *(const bf16x8*)(smem + K2_ZN + row * 256 + (kb ^ ((row & 7) << 4)));
    }
  }

  auto mfma_from = [&](f32x4 (&acc)[2][4], int wboff) {
#pragma unroll
    for (int kk = 0; kk < 4; ++kk) {
      int kb = kk * 64 + gq * 16;
      bf16x8 wf[4];
#pragma unroll
      for (int n = 0; n < 4; ++n) {
        int row = n * 16 + rl;
        wf[n] = *(const bf16x8*)(smem + wboff + row * 256 + (kb ^ ((row & 7) << 4)));
      }
#pragma unroll
      for (int r = 0; r < 2; ++r)
#pragma unroll
        for (int n = 0; n < 4; ++n)
          acc[r][n] = __builtin_amdgcn_mfma_f32_16x16x32_bf16(afr[kk][r], wf[n], acc[r][n], 0, 0, 0);
    }
  };

  auto store_epi = [&](ushort_t* dst) {
#pragma unroll
    for (int pass = 0; pass < 4; ++pass) {
      int idx = pass * 256 + t;
      int c = idx >> 4, k = idx & 15;
      u16x8 v = *(const u16x8*)(smem + c * 256 + ((k * 16) ^ ((c & 7) << 4)));
      *(u16x8*)(dst + (size_t)c * NN + k * 8) = v;
    }
  };

  // ---- 4 ab iterations: p rows ci*64 (WB0), g rows 256+ci*64 (WB1) ----
  for (int ci = 0; ci < 4; ++ci) {
    f32x4 accp[2][4] = {}, accg[2][4] = {};
    mfma_from(accp, K2_WB0);
    mfma_from(accg, K2_WB1);
    __syncthreads();                         // WB reads done; prev store's epi reads done
    if (ci < 3) {
      stage_wb((ci + 1) * 64, K2_WB0);       // next p
      stage_wb(256 + (ci + 1) * 64, K2_WB1); // next g
    }
    // epilogue: p*sigm(g)*mask -> epi [64ch][256B] XOR-swizzled @0
#pragma unroll
    for (int r = 0; r < 2; ++r) {
      int ijbase = wid * 32 + r * 16 + gq * 4;
      float4 mv = *(const float4*)(mask + ij0 + ijbase);
      float m4[4] = {mv.x, mv.y, mv.z, mv.w};
#pragma unroll
      for (int n = 0; n < 4; ++n) {
        int ch = n * 16 + rl;
        float pbv = bp[ci * 64 + ch], gbv = bg[ci * 64 + ch];
        u16x4 pk;
#pragma unroll
        for (int reg = 0; reg < 4; ++reg) {
          float pv = accp[r][n][reg] + pbv;
          float gv = sigm(accg[r][n][reg] + gbv);
          pk[reg] = f2bf(pv * gv * m4[reg]);
        }
        *(u16x4*)(smem + ch * 256 + ((ijbase * 2) ^ ((ch & 7) << 4))) = pk;
      }
    }
    __syncthreads();                         // epi ready; drains stage vmcnt
    store_epi(((ci < 2) ? a_t : b_t) + (size_t)((ci & 1) * 64) * NN + ij0);
    // no trailing barrier: next iter's first __syncthreads protects epi
  }
}

// ---------------- K3: per-channel triangle GEMM (R3-proven single-buffer) --------
// x[i,j,c] = sum_k a[i,k,c]*b[j,k,c]; a_t/b_t channel-major NT layout.
// x output is TILED: x_t[tile=ij/64][c][ij%64] (8192 elems / 16KB per tile).
__global__ __launch_bounds__(256, 2) void k3_tri(const ushort_t* __restrict__ a_t,
                                                 const ushort_t* __restrict__ b_t,
                                                 ushort_t* __restrict__ x_t) {
  __shared__ __align__(16) char smem[34816];  // stage A[0,16K)+B[16K,32K); epi union
  int p = blockIdx.x;
  int xcd = p & 7, s = p >> 3;
  int tile = s % 36, c = xcd + 8 * (s / 36);
  int ti = tile / 6, tj = tile % 6;
  int i0 = ti * 128, j0 = tj * 128;
  const char* pa = (const char*)(a_t + (size_t)c * NN);
  const char* pb = (const char*)(b_t + (size_t)c * NN);
  int t = threadIdx.x, lane = t & 63, wid = t >> 6;
  int rl = lane & 15, gq = lane >> 4;
  int wj = (wid >> 1) * 64, wi = (wid & 1) * 64;
  f32x4 acc[4][4] = {};

  for (int ks = 0; ks < 12; ++ks) {
#pragma unroll
    for (int iss = 0; iss < 4; ++iss) {
      int idx = iss * 256 + wid * 64 + lane;
      int row = idx >> 3, slot = idx & 7;
      int gb = (slot * 16) ^ ((row & 7) << 4);
      gload16(pa + (size_t)(i0 + row) * 1536 + ks * 128 + gb,
              smem + (iss * 256 + wid * 64) * 16);
      gload16(pb + (size_t)(j0 + row) * 1536 + ks * 128 + gb,
              smem + 16384 + (iss * 256 + wid * 64) * 16);
    }
    __syncthreads();
#pragma unroll
    for (int kk = 0; kk < 2; ++kk) {
      int kb = kk * 64 + gq * 16;
      bf16x8 af[4], bf[4];
#pragma unroll
      for (int f = 0; f < 4; ++f) {
        int rowi = wi + f * 16 + rl;
        af[f] = *(const bf16x8*)(smem + rowi * 128 + (kb ^ ((rowi & 7) << 4)));
        int rowj = wj + f * 16 + rl;
        bf[f] = *(const bf16x8*)(smem + 16384 + rowj * 128 + (kb ^ ((rowj & 7) << 4)));
      }
#pragma unroll
      for (int fj = 0; fj < 4; ++fj)
#pragma unroll
        for (int fi = 0; fi < 4; ++fi)
          acc[fj][fi] = __builtin_amdgcn_mfma_f32_16x16x32_bf16(bf[fj], af[fi], acc[fj][fi], 0, 0, 0);
    }
    __syncthreads();
  }
  // epilogue: D[j][i]; lane col = i (fixed), rows = j consecutive -> epi[i][j]
  char* epi = smem;  // [128][136] bf16, pitch 272B
#pragma unroll
  for (int fj = 0; fj < 4; ++fj) {
    int jbase = wj + fj * 16 + gq * 4;
#pragma unroll
    for (int fi = 0; fi < 4; ++fi) {
      int i = wi + fi * 16 + rl;
      u16x4 pk;
#pragma unroll
      for (int reg = 0; reg < 4; ++reg) pk[reg] = f2bf(acc[fj][fi][reg]);
      *(u16x4*)(epi + i * 272 + jbase * 2) = pk;
    }
  }
  __syncthreads();
#pragma unroll
  for (int pass = 0; pass < 8; ++pass) {
    int idx = pass * 256 + t;
    int row = idx >> 4, chunk = idx & 15;
    u16x8 v = *(const u16x8*)(epi + row * 272 + chunk * 16);
    // tiled store: ij = (i0+row)*768 + j0 + chunk*8
    int xtile = (i0 + row) * 12 + (j0 >> 6) + (chunk >> 3);
    *(u16x8*)(x_t + (size_t)xtile * 8192 + c * 64 + (chunk & 7) * 8) = v;
  }
}

// ---------------- K4: LN(x) @ zw^T + zb, * sigm(zn @ Wgate^T + bgate) ------------
// Register-lean row-per-thread LN: thread owns row ij=t>>2, channels c=(t&3)+4k;
// 2-step quad reduce; x values re-read from LDS (not cached); weight frags read
// from global in-loop (R9/R10-proven neutral). LDS 35840 -> 4 blocks/CU:
//   CB  @0      (2048)  zbias|wout|bout|bgate f32
//   ZN  @2048   (16384) 64x256B swz (gate GEMM A; dead after gate GEMM)
//   XN  @2048   overlays ZN after barrier #2 (LN outputs, [ij][256B swz])
//   X   @18432  (16384) [c][128B ^ ((c&7)<<4)]; live until OUT epi
//   OUT @2048   (33792) [64][132] f32 over ZN/XN+X after barrier #4
constexpr int K4_CB  = 0;
constexpr int K4_ZN  = 2048;
constexpr int K4_XN  = 2048;
constexpr int K4_X   = 18432;
constexpr int K4_OUT = 2048;
__global__ __launch_bounds__(256, 4) void k4_out(
    const ushort_t* __restrict__ x_t, const ushort_t* __restrict__ zn,
    const ushort_t* __restrict__ zwb, const ushort_t* __restrict__ wgateb,
    const float* __restrict__ wout, const float* __restrict__ bout,
    const float* __restrict__ zbias, const float* __restrict__ bgate,
    float* __restrict__ out) {
  __shared__ __align__(16) char smem[35840];
  int ij0 = blockIdx.x * 64;
  int t = threadIdx.x, lane = t & 63, wid = t >> 6;
  int rl = lane & 15, gq = lane >> 4;
  int wrow = (wid >> 1) * 32, wcol = (wid & 1) * 64;

  // stage zn tile (64x256B, pre-swizzled source) -> ZN
  {
    const char* base = (const char*)(zn + (size_t)ij0 * C);
#pragma unroll
    for (int iss = 0; iss < 4; ++iss) {
      int idx = iss * 256 + t;
      int row = idx >> 4, slot = idx & 15;
      int gcol = (slot * 16) ^ ((row & 7) << 4);
      gload16(base + row * 256 + gcol, smem + K4_ZN + idx * 16);
    }
  }
  // stage x tile: global tile [c][64] is linear; pre-swizzle SOURCE, linear LDS dest
  {
    const char* xsrc = (const char*)(x_t + (size_t)blockIdx.x * 8192);
#pragma unroll
    for (int pass = 0; pass < 4; ++pass) {
      int idx = pass * 256 + t;
      int c = idx >> 3, chunk = idx & 7;
      int gb = (chunk * 16) ^ ((c & 7) << 4);
      gload16(xsrc + c * 128 + gb, smem + K4_X + idx * 16);
    }
  }
  if (t < 128) {
    *(float*)(smem + K4_CB + t * 4)        = zbias[t];
    *(float*)(smem + K4_CB + 512 + t * 4)  = wout[t];
    *(float*)(smem + K4_CB + 1024 + t * 4) = bout[t];
    *(float*)(smem + K4_CB + 1536 + t * 4) = bgate[t];
  }
  __syncthreads();   // #1: staging complete

  const float* cb = (const float*)(smem + K4_CB);

  // LN stats: row ij = t>>2, channels c = (t&3)+4k; values NOT cached (re-read later)
  int ij = t >> 2, cq = t & 3;
  float sm = 0.f, sq = 0.f;
#pragma unroll
  for (int k = 0; k < 32; ++k) {
    int c = cq + k * 4;
    float v = bf2f(*(const ushort_t*)(smem + K4_X + c * 128 + ((ij * 2) ^ ((c & 7) << 4))));
    sm += v; sq += v * v;
  }
  sm += __shfl_xor(sm, 1); sm += __shfl_xor(sm, 2);
  sq += __shfl_xor(sq, 1); sq += __shfl_xor(sq, 2);
  float mean = sm * (1.f / 128.f);
  float rstd = rsqrtf(sq * (1.f / 128.f) - mean * mean + 1e-5f);

  // gate GEMM: ZN (LDS) @ wgate (global, in-loop frags) -> acc2
  f32x4 acc2[2][4] = {};
#pragma unroll
  for (int kk = 0; kk < 4; ++kk) {
    int kb = kk * 64 + gq * 16;
    bf16x8 a2[2], wf[4];
#pragma unroll
    for (int r = 0; r < 2; ++r) {
      int row = wrow + r * 16 + rl;
      a2[r] = *(const bf16x8*)(smem + K4_ZN + row * 256 + (kb ^ ((row & 7) << 4)));
    }
#pragma unroll
    for (int n = 0; n < 4; ++n) {
      int d = wcol + n * 16 + rl;
      wf[n] = *(const bf16x8*)(wgateb + (size_t)d * C + kk * 32 + gq * 8);
    }
#pragma unroll
    for (int r = 0; r < 2; ++r)
#pragma unroll
      for (int n = 0; n < 4; ++n)
        acc2[r][n] = __builtin_amdgcn_mfma_f32_16x16x32_bf16(a2[r], wf[n], acc2[r][n], 0, 0, 0);
  }
  __syncthreads();   // #2: ZN reads done -> ZN region becomes XN

  // LN outputs: re-read X, write XN (overlaying dead ZN)
#pragma unroll
  for (int k = 0; k < 32; ++k) {
    int c = cq + k * 4;
    float v = bf2f(*(const ushort_t*)(smem + K4_X + c * 128 + ((ij * 2) ^ ((c & 7) << 4))));
    float o = (v - mean) * rstd * cb[128 + c] + cb[256 + c];
    *(ushort_t*)(smem + K4_XN + ij * 256 + ((c * 2) ^ ((ij & 7) << 4))) = f2bf(o);
  }
  __syncthreads();   // #3: XN visible to all waves

  // zw GEMM: XN (LDS) @ zwb (global, in-loop frags) -> acc
  f32x4 acc[2][4] = {};
#pragma unroll
  for (int kk = 0; kk < 4; ++kk) {
    int kb = kk * 64 + gq * 16;
    bf16x8 a[2], wf[4];
#pragma unroll
    for (int r = 0; r < 2; ++r) {
      int row = wrow + r * 16 + rl;
      a[r] = *(const bf16x8*)(smem + K4_XN + row * 256 + (kb ^ ((row & 7) << 4)));
    }
#pragma unroll
    for (int n = 0; n < 4; ++n) {
      int d = wcol + n * 16 + rl;
      wf[n] = *(const bf16x8*)(zwb + (size_t)d * C + kk * 32 + gq * 8);
    }
#pragma unroll
    for (int r = 0; r < 2; ++r)
#pragma unroll
      for (int n = 0; n < 4; ++n)
        acc[r][n] = __builtin_amdgcn_mfma_f32_16x16x32_bf16(a[r], wf[n], acc[r][n], 0, 0, 0);
  }
  __syncthreads();   // #4: XN reads done; OUT overlays XN+X

  float* outl = (float*)(smem + K4_OUT);  // [64][132] f32
#pragma unroll
  for (int r = 0; r < 2; ++r) {
    int ijbase = wrow + r * 16 + gq * 4;
#pragma unroll
    for (int n = 0; n < 4; ++n) {
      int d = wcol + n * 16 + rl;
      float zb = cb[d];
      float gb = cb[384 + d];
#pragma unroll
      for (int reg = 0; reg < 4; ++reg)
        outl[(ijbase + reg) * 132 + d] =
            (acc[r][n][reg] + zb) * sigm(acc2[r][n][reg] + gb);
    }
  }
  __syncthreads();   // #5
#pragma unroll
  for (int pass = 0; pass < 8; ++pass) {
    int idx = pass * 256 + t;
    int row = idx >> 5, ch4 = idx & 31;
    float4 v = *(const float4*)(smem + K4_OUT + row * 528 + ch4 * 16);
    *(float4*)(out + (size_t)(ij0 + row) * C + ch4 * 4) = v;
  }
}

extern "C" void kernel_launch(void* const* d_in, const int* in_sizes, int n_in,
                              void* d_out, int out_size, void* d_ws, size_t ws_size,
                              hipStream_t stream) {
  const float* z     = (const float*)d_in[0];
  const float* mask  = (const float*)d_in[1];
  const float* w_in  = (const float*)d_in[2];
  const float* b_in  = (const float*)d_in[3];
  const float* Wp    = (const float*)d_in[4];
  const float* bp    = (const float*)d_in[5];
  const float* Wg    = (const float*)d_in[6];
  const float* bg    = (const float*)d_in[7];
  const float* Wgate = (const float*)d_in[8];
  const float* bgate = (const float*)d_in[9];
  const float* w_out = (const float*)d_in[10];
  const float* b_out = (const float*)d_in[11];
  const float* zw    = (const float*)d_in[12];
  const float* zb    = (const float*)d_in[13];

  // ws: zwb(16K elems) | Wall(80K elems) | zn (live thru k4) | x_t (tiled)
  ushort_t* zwb  = (ushort_t*)d_ws;
  ushort_t* Wall = zwb + 16384;
  ushort_t* zn   = Wall + 81920;
  ushort_t* x_t  = zn + (size_t)NN * C;
  // a_t/b_t live inside d_out (2 bf16 planes == fp32 output bytes); K4 overwrites last.
  ushort_t* a_t = (ushort_t*)d_out;
  ushort_t* b_t = a_t + (size_t)NN * C;
  float* outp = (float*)d_out;

  k1_ln<<<NN / 4, 256, 0, stream>>>(z, w_in, b_in, zn);
  k0_cvt<<<384, 256, 0, stream>>>(zw, Wp, Wg, Wgate, zwb, Wall);
  k2_proj<<<4608, 256, 0, stream>>>(zn, Wall, bp, bg, mask, a_t, b_t);
  k3_tri<<<4608, 256, 0, stream>>>(a_t, b_t, x_t);
  k4_out<<<9216, 256, 0, stream>>>(x_t, zn, zwb, Wall + (size_t)512 * C,
                                   w_out, b_out, zb, bgate, outp);
}

// Round 14
// 609.838 us; speedup vs baseline: 1.1554x; 1.1554x over previous
//
#include <hip/hip_runtime.h>

typedef unsigned short ushort_t;
typedef __attribute__((ext_vector_type(4))) unsigned short u16x4;
typedef __attribute__((ext_vector_type(8))) unsigned short u16x8;
typedef __attribute__((ext_vector_type(2))) unsigned short u16x2;
typedef __attribute__((ext_vector_type(4))) float f32x4;
typedef __attribute__((ext_vector_type(8))) __bf16 bf16x8;

constexpr int N_ = 768;
constexpr int NN = N_ * N_;   // 589824
constexpr int C  = 128;

__device__ __forceinline__ unsigned short f2bf(float f) {
  union { float f; unsigned int u; } v; v.f = f;
  unsigned int r = v.u + 0x7fffu + ((v.u >> 16) & 1u);
  return (unsigned short)(r >> 16);
}
__device__ __forceinline__ float bf2f(unsigned short u) {
  union { unsigned int i; float f; } v; v.i = ((unsigned int)u) << 16;
  return v.f;
}
// sigmoid with hardware reciprocal (1 op vs ~8-op exact divide); ~2^-22 rel err
__device__ __forceinline__ float sigm(float x) {
  return __builtin_amdgcn_rcpf(1.f + __expf(-x));
}

__device__ __forceinline__ void gload16(const void* g, void* l) {
  __builtin_amdgcn_global_load_lds(
      (const __attribute__((address_space(1))) unsigned int*)g,
      (__attribute__((address_space(3))) unsigned int*)l, 16, 0, 0);
}

// ---------------- K1: LayerNorm(z) -> zn bf16 (ij,c) ----------------
__global__ __launch_bounds__(256) void k1_ln(const float* __restrict__ z,
                                             const float* __restrict__ w,
                                             const float* __restrict__ b,
                                             ushort_t* __restrict__ zn) {
  int row  = blockIdx.x * 4 + (threadIdx.x >> 6);
  int lane = threadIdx.x & 63;
  const float* src = z + (size_t)row * C;
  float2 v = *(const float2*)(src + lane * 2);
  float sm = v.x + v.y;
#pragma unroll
  for (int m = 1; m < 64; m <<= 1) sm += __shfl_xor(sm, m);
  float mean = sm * (1.f / 128.f);
  float d0 = v.x - mean, d1 = v.y - mean;
  float sq = d0 * d0 + d1 * d1;
#pragma unroll
  for (int m = 1; m < 64; m <<= 1) sq += __shfl_xor(sq, m);
  float rstd = rsqrtf(sq * (1.f / 128.f) + 1e-5f);
  float2 wv = *(const float2*)(w + lane * 2);
  float2 bv = *(const float2*)(b + lane * 2);
  u16x2 o; o.x = f2bf(d0 * rstd * wv.x + bv.x); o.y = f2bf(d1 * rstd * wv.y + bv.y);
  *(u16x2*)(zn + (size_t)row * C + lane * 2) = o;
}

// ---------------- K0: weights fp32 -> bf16 (zwb + Wall=[Wp;Wg;Wgate]) ----------------
__global__ void k0_cvt(const float* __restrict__ zw, const float* __restrict__ Wp,
                       const float* __restrict__ Wg, const float* __restrict__ Wgate,
                       ushort_t* __restrict__ zwb, ushort_t* __restrict__ Wall) {
  int i = blockIdx.x * 256 + threadIdx.x;
  if (i < 16384) zwb[i] = f2bf(zw[i]);
  if (i < 81920) {
    float v = (i < 32768) ? Wp[i] : (i < 65536 ? Wg[i - 32768] : Wgate[i - 65536]);
    Wall[i] = f2bf(v);
  }
}

// ---------------- K2: a/b projections only, dual-W-buffer loop ----------------
// Wall rows: p [0,256), g [256,512). (gate rows 512+ consumed by k4 now.)
// LDS 64K: zn 32K @0 (dead after afr hoist; epi 16K overlays @0) | WB0 16K | WB1 16K.
constexpr int K2_ZN  = 0;
constexpr int K2_WB0 = 32768;
constexpr int K2_WB1 = 49152;
__global__ __launch_bounds__(256, 2) void k2_proj(
    const ushort_t* __restrict__ zn, const ushort_t* __restrict__ Wall,
    const float* __restrict__ bp, const float* __restrict__ bg,
    const float* __restrict__ mask,
    ushort_t* __restrict__ a_t, ushort_t* __restrict__ b_t) {
  __shared__ __align__(16) char smem[65536];
  int ij0 = blockIdx.x * 128;
  int t = threadIdx.x, lane = t & 63, wid = t >> 6;
  int rl = lane & 15, gq = lane >> 4;

  auto stage_wb = [&](int wrowbase, int wboff) {
#pragma unroll
    for (int pass = 0; pass < 4; ++pass) {
      int idx = pass * 256 + t;
      int row = idx >> 4, slot = idx & 15;
      int gcol = (slot * 16) ^ ((row & 7) << 4);
      gload16((const char*)Wall + (size_t)(wrowbase + row) * 256 + gcol,
              smem + wboff + idx * 16);
    }
  };

  // prologue: stage zn tile (pre-swizzled source) + first p/g chunk pair
  {
    const char* base = (const char*)(zn + (size_t)ij0 * C);
#pragma unroll
    for (int iss = 0; iss < 8; ++iss) {
      int idx = iss * 256 + t;
      int row = idx >> 4, slot = idx & 15;
      int gcol = (slot * 16) ^ ((row & 7) << 4);
      gload16(base + row * 256 + gcol, smem + K2_ZN + idx * 16);
    }
  }
  stage_wb(0, K2_WB0);
  stage_wb(256, K2_WB1);
  __syncthreads();

  // hoist A-fragments (this wave's 32 zn rows); zn LDS dead afterwards
  bf16x8 afr[4][2];
#pragma unroll
  for (int kk = 0; kk < 4; ++kk) {
    int kb = kk * 64 + gq * 16;
#pragma unroll
    for (int r = 0; r < 2; ++r) {
      int row = wid * 32 + r * 16 + rl;
      afr[kk][r] = *(const bf16x8*)(smem + K2_ZN + row * 256 + (kb ^ ((row & 7) << 4)));
    }
  }

  auto mfma_from = [&](f32x4 (&acc)[2][4], int wboff) {
#pragma unroll
    for (int kk = 0; kk < 4; ++kk) {
      int kb = kk * 64 + gq * 16;
      bf16x8 wf[4];
#pragma unroll
      for (int n = 0; n < 4; ++n) {
        int row = n * 16 + rl;
        wf[n] = *(const bf16x8*)(smem + wboff + row * 256 + (kb ^ ((row & 7) << 4)));
      }
#pragma unroll
      for (int r = 0; r < 2; ++r)
#pragma unroll
        for (int n = 0; n < 4; ++n)
          acc[r][n] = __builtin_amdgcn_mfma_f32_16x16x32_bf16(afr[kk][r], wf[n], acc[r][n], 0, 0, 0);
    }
  };

  auto store_epi = [&](ushort_t* dst) {
#pragma unroll
    for (int pass = 0; pass < 4; ++pass) {
      int idx = pass * 256 + t;
      int c = idx >> 4, k = idx & 15;
      u16x8 v = *(const u16x8*)(smem + c * 256 + ((k * 16) ^ ((c & 7) << 4)));
      *(u16x8*)(dst + (size_t)c * NN + k * 8) = v;
    }
  };

  // ---- 4 ab iterations: p rows ci*64 (WB0), g rows 256+ci*64 (WB1) ----
  for (int ci = 0; ci < 4; ++ci) {
    f32x4 accp[2][4] = {}, accg[2][4] = {};
    mfma_from(accp, K2_WB0);
    mfma_from(accg, K2_WB1);
    __syncthreads();                         // WB reads done; prev store's epi reads done
    if (ci < 3) {
      stage_wb((ci + 1) * 64, K2_WB0);       // next p
      stage_wb(256 + (ci + 1) * 64, K2_WB1); // next g
    }
    // epilogue: p*sigm(g)*mask -> epi [64ch][256B] XOR-swizzled @0
#pragma unroll
    for (int r = 0; r < 2; ++r) {
      int ijbase = wid * 32 + r * 16 + gq * 4;
      float4 mv = *(const float4*)(mask + ij0 + ijbase);
      float m4[4] = {mv.x, mv.y, mv.z, mv.w};
#pragma unroll
      for (int n = 0; n < 4; ++n) {
        int ch = n * 16 + rl;
        float pbv = bp[ci * 64 + ch], gbv = bg[ci * 64 + ch];
        u16x4 pk;
#pragma unroll
        for (int reg = 0; reg < 4; ++reg) {
          float pv = accp[r][n][reg] + pbv;
          float gv = sigm(accg[r][n][reg] + gbv);
          pk[reg] = f2bf(pv * gv * m4[reg]);
        }
        *(u16x4*)(smem + ch * 256 + ((ijbase * 2) ^ ((ch & 7) << 4))) = pk;
      }
    }
    __syncthreads();                         // epi ready; drains stage vmcnt
    store_epi(((ci < 2) ? a_t : b_t) + (size_t)((ci & 1) * 64) * NN + ij0);
    // no trailing barrier: next iter's first __syncthreads protects epi
  }
}

// ---------------- K3: per-channel triangle GEMM (R3-proven single-buffer) --------
// x[i,j,c] = sum_k a[i,k,c]*b[j,k,c]; a_t/b_t channel-major NT layout.
// x output is TILED: x_t[tile=ij/64][c][ij%64] (8192 elems / 16KB per tile).
__global__ __launch_bounds__(256, 2) void k3_tri(const ushort_t* __restrict__ a_t,
                                                 const ushort_t* __restrict__ b_t,
                                                 ushort_t* __restrict__ x_t) {
  __shared__ __align__(16) char smem[34816];  // stage A[0,16K)+B[16K,32K); epi union
  int p = blockIdx.x;
  int xcd = p & 7, s = p >> 3;
  int tile = s % 36, c = xcd + 8 * (s / 36);
  int ti = tile / 6, tj = tile % 6;
  int i0 = ti * 128, j0 = tj * 128;
  const char* pa = (const char*)(a_t + (size_t)c * NN);
  const char* pb = (const char*)(b_t + (size_t)c * NN);
  int t = threadIdx.x, lane = t & 63, wid = t >> 6;
  int rl = lane & 15, gq = lane >> 4;
  int wj = (wid >> 1) * 64, wi = (wid & 1) * 64;
  f32x4 acc[4][4] = {};

  for (int ks = 0; ks < 12; ++ks) {
#pragma unroll
    for (int iss = 0; iss < 4; ++iss) {
      int idx = iss * 256 + wid * 64 + lane;
      int row = idx >> 3, slot = idx & 7;
      int gb = (slot * 16) ^ ((row & 7) << 4);
      gload16(pa + (size_t)(i0 + row) * 1536 + ks * 128 + gb,
              smem + (iss * 256 + wid * 64) * 16);
      gload16(pb + (size_t)(j0 + row) * 1536 + ks * 128 + gb,
              smem + 16384 + (iss * 256 + wid * 64) * 16);
    }
    __syncthreads();
#pragma unroll
    for (int kk = 0; kk < 2; ++kk) {
      int kb = kk * 64 + gq * 16;
      bf16x8 af[4], bf[4];
#pragma unroll
      for (int f = 0; f < 4; ++f) {
        int rowi = wi + f * 16 + rl;
        af[f] = *(const bf16x8*)(smem + rowi * 128 + (kb ^ ((rowi & 7) << 4)));
        int rowj = wj + f * 16 + rl;
        bf[f] = *(const bf16x8*)(smem + 16384 + rowj * 128 + (kb ^ ((rowj & 7) << 4)));
      }
#pragma unroll
      for (int fj = 0; fj < 4; ++fj)
#pragma unroll
        for (int fi = 0; fi < 4; ++fi)
          acc[fj][fi] = __builtin_amdgcn_mfma_f32_16x16x32_bf16(bf[fj], af[fi], acc[fj][fi], 0, 0, 0);
    }
    __syncthreads();
  }
  // epilogue: D[j][i]; lane col = i (fixed), rows = j consecutive -> epi[i][j]
  char* epi = smem;  // [128][136] bf16, pitch 272B
#pragma unroll
  for (int fj = 0; fj < 4; ++fj) {
    int jbase = wj + fj * 16 + gq * 4;
#pragma unroll
    for (int fi = 0; fi < 4; ++fi) {
      int i = wi + fi * 16 + rl;
      u16x4 pk;
#pragma unroll
      for (int reg = 0; reg < 4; ++reg) pk[reg] = f2bf(acc[fj][fi][reg]);
      *(u16x4*)(epi + i * 272 + jbase * 2) = pk;
    }
  }
  __syncthreads();
#pragma unroll
  for (int pass = 0; pass < 8; ++pass) {
    int idx = pass * 256 + t;
    int row = idx >> 4, chunk = idx & 15;
    u16x8 v = *(const u16x8*)(epi + row * 272 + chunk * 16);
    // tiled store: ij = (i0+row)*768 + j0 + chunk*8
    int xtile = (i0 + row) * 12 + (j0 >> 6) + (chunk >> 3);
    *(u16x8*)(x_t + (size_t)xtile * 8192 + c * 64 + (chunk & 7) * 8) = v;
  }
}

// ---------------- K4: LN(x) @ zw^T + zb, * sigm(zn @ Wgate^T + bgate) ------------
// R11 structure ((256,2), LDS 52224, 3 blocks/CU) with ONLY the LN phase swapped
// to row-per-thread (validated in R13): thread owns row ij=t>>2, channels
// c=(t&3)+4k; 2-step quad shfl reduce; X re-read for normalize (register-lean).
// CB 0..2048 | ZN 2048..18432 (64x256B swz) | X 18432..35840 ([128c][136B])
// | XN 35840..52224 (64x256B swz) | OUT overlays X+XN @18432. 
constexpr int K4_CB  = 0;
constexpr int K4_ZN  = 2048;
constexpr int K4_X   = 18432;
constexpr int K4_XN  = 35840;
constexpr int K4_OUT = 18432;
__global__ __launch_bounds__(256, 2) void k4_out(
    const ushort_t* __restrict__ x_t, const ushort_t* __restrict__ zn,
    const ushort_t* __restrict__ zwb, const ushort_t* __restrict__ wgateb,
    const float* __restrict__ wout, const float* __restrict__ bout,
    const float* __restrict__ zbias, const float* __restrict__ bgate,
    float* __restrict__ out) {
  __shared__ __align__(16) char smem[52224];
  int ij0 = blockIdx.x * 64;
  int t = threadIdx.x, lane = t & 63, wid = t >> 6;
  int rl = lane & 15, gq = lane >> 4;
  int wrow = (wid >> 1) * 32, wcol = (wid & 1) * 64;

  // prefetch gate-weight fragments into registers (compiler may sink; harmless)
  bf16x8 wgfr[4][4];
#pragma unroll
  for (int kk = 0; kk < 4; ++kk)
#pragma unroll
    for (int n = 0; n < 4; ++n) {
      int d = wcol + n * 16 + rl;
      wgfr[kk][n] = *(const bf16x8*)(wgateb + (size_t)d * C + kk * 32 + gq * 8);
    }

  // stage zn tile (64 rows x 256B, pre-swizzled source) -> ZN
  {
    const char* base = (const char*)(zn + (size_t)ij0 * C);
#pragma unroll
    for (int iss = 0; iss < 4; ++iss) {
      int idx = iss * 256 + t;
      int row = idx >> 4, slot = idx & 15;
      int gcol = (slot * 16) ^ ((row & 7) << 4);
      gload16(base + row * 256 + gcol, smem + K4_ZN + idx * 16);
    }
  }
  // stage x: tiled layout -> fully linear contiguous 16KB read -> X [c][136B]
  {
    const ushort_t* xsrc = x_t + (size_t)blockIdx.x * 8192;
#pragma unroll
    for (int pass = 0; pass < 4; ++pass) {
      int idx = pass * 256 + t;
      int c = idx >> 3, chunk = idx & 7;
      u16x8 vx = *(const u16x8*)(xsrc + idx * 8);
      u16x4 lo, hi;
      lo[0]=vx[0]; lo[1]=vx[1]; lo[2]=vx[2]; lo[3]=vx[3];
      hi[0]=vx[4]; hi[1]=vx[5]; hi[2]=vx[6]; hi[3]=vx[7];
      *(u16x4*)(smem + K4_X + c * 136 + chunk * 16) = lo;
      *(u16x4*)(smem + K4_X + c * 136 + chunk * 16 + 8) = hi;
    }
  }
  if (t < 128) {
    *(float*)(smem + K4_CB + t * 4)        = zbias[t];
    *(float*)(smem + K4_CB + 512 + t * 4)  = wout[t];
    *(float*)(smem + K4_CB + 1024 + t * 4) = bout[t];
    *(float*)(smem + K4_CB + 1536 + t * 4) = bgate[t];
  }
  __syncthreads();   // #1: staging complete

  const float* cb = (const float*)(smem + K4_CB);

  // Row-per-thread LN (R13-validated math, R11 layout): row ij=t>>2, c=(t&3)+4k.
  {
    int ij = t >> 2, cq = t & 3;
    float sm = 0.f, sq = 0.f;
#pragma unroll
    for (int k = 0; k < 32; ++k) {
      int c = cq + k * 4;
      float v = bf2f(*(const ushort_t*)(smem + K4_X + c * 136 + ij * 2));
      sm += v; sq += v * v;
    }
    sm += __shfl_xor(sm, 1); sm += __shfl_xor(sm, 2);
    sq += __shfl_xor(sq, 1); sq += __shfl_xor(sq, 2);
    float mean = sm * (1.f / 128.f);
    float rstd = rsqrtf(sq * (1.f / 128.f) - mean * mean + 1e-5f);
#pragma unroll
    for (int k = 0; k < 32; ++k) {
      int c = cq + k * 4;
      float v = bf2f(*(const ushort_t*)(smem + K4_X + c * 136 + ij * 2));
      float o = (v - mean) * rstd * cb[128 + c] + cb[256 + c];
      *(ushort_t*)(smem + K4_XN + ij * 256 + ((c * 2) ^ ((ij & 7) << 4))) = f2bf(o);
    }
  }

  // gate GEMM: zn (LDS, swizzled) @ wgfr (regs) -> acc2
  f32x4 acc2[2][4] = {};
#pragma unroll
  for (int kk = 0; kk < 4; ++kk) {
    int kb = kk * 64 + gq * 16;
    bf16x8 a2[2];
#pragma unroll
    for (int r = 0; r < 2; ++r) {
      int row = wrow + r * 16 + rl;
      a2[r] = *(const bf16x8*)(smem + K4_ZN + row * 256 + (kb ^ ((row & 7) << 4)));
    }
#pragma unroll
    for (int r = 0; r < 2; ++r)
#pragma unroll
      for (int n = 0; n < 4; ++n)
        acc2[r][n] = __builtin_amdgcn_mfma_f32_16x16x32_bf16(a2[r], wgfr[kk][n], acc2[r][n], 0, 0, 0);
  }

  // prefetch zw-weight fragments (fly across the barrier wait)
  bf16x8 zwfr[4][4];
#pragma unroll
  for (int kk = 0; kk < 4; ++kk)
#pragma unroll
    for (int n = 0; n < 4; ++n) {
      int d = wcol + n * 16 + rl;
      zwfr[kk][n] = *(const bf16x8*)(zwb + (size_t)d * C + kk * 32 + gq * 8);
    }
  __syncthreads();   // #2: all waves' LN writes to XN visible

  // zw GEMM: xn (LDS, swizzled) @ zwfr (regs) -> acc
  f32x4 acc[2][4] = {};
#pragma unroll
  for (int kk = 0; kk < 4; ++kk) {
    int kb = kk * 64 + gq * 16;
    bf16x8 a[2];
#pragma unroll
    for (int r = 0; r < 2; ++r) {
      int row = wrow + r * 16 + rl;
      a[r] = *(const bf16x8*)(smem + K4_XN + row * 256 + (kb ^ ((row & 7) << 4)));
    }
#pragma unroll
    for (int r = 0; r < 2; ++r)
#pragma unroll
      for (int n = 0; n < 4; ++n)
        acc[r][n] = __builtin_amdgcn_mfma_f32_16x16x32_bf16(a[r], zwfr[kk][n], acc[r][n], 0, 0, 0);
  }
  __syncthreads();  // #3: XN reads done; OUT overlays X+XN

  float* outl = (float*)(smem + K4_OUT);  // [64][132] f32
#pragma unroll
  for (int r = 0; r < 2; ++r) {
    int ijbase = wrow + r * 16 + gq * 4;
#pragma unroll
    for (int n = 0; n < 4; ++n) {
      int d = wcol + n * 16 + rl;
      float zb = cb[d];
      float gb = cb[384 + d];
#pragma unroll
      for (int reg = 0; reg < 4; ++reg)
        outl[(ijbase + reg) * 132 + d] =
            (acc[r][n][reg] + zb) * sigm(acc2[r][n][reg] + gb);
    }
  }
  __syncthreads();   // #4
#pragma unroll
  for (int pass = 0; pass < 8; ++pass) {
    int idx = pass * 256 + t;
    int row = idx >> 5, ch4 = idx & 31;
    float4 v = *(const float4*)(smem + K4_OUT + row * 528 + ch4 * 16);
    *(float4*)(out + (size_t)(ij0 + row) * C + ch4 * 4) = v;
  }
}

extern "C" void kernel_launch(void* const* d_in, const int* in_sizes, int n_in,
                              void* d_out, int out_size, void* d_ws, size_t ws_size,
                              hipStream_t stream) {
  const float* z     = (const float*)d_in[0];
  const float* mask  = (const float*)d_in[1];
  const float* w_in  = (const float*)d_in[2];
  const float* b_in  = (const float*)d_in[3];
  const float* Wp    = (const float*)d_in[4];
  const float* bp    = (const float*)d_in[5];
  const float* Wg    = (const float*)d_in[6];
  const float* bg    = (const float*)d_in[7];
  const float* Wgate = (const float*)d_in[8];
  const float* bgate = (const float*)d_in[9];
  const float* w_out = (const float*)d_in[10];
  const float* b_out = (const float*)d_in[11];
  const float* zw    = (const float*)d_in[12];
  const float* zb    = (const float*)d_in[13];

  // ws: zwb(16K elems) | Wall(80K elems) | zn (live thru k4) | x_t (tiled)
  ushort_t* zwb  = (ushort_t*)d_ws;
  ushort_t* Wall = zwb + 16384;
  ushort_t* zn   = Wall + 81920;
  ushort_t* x_t  = zn + (size_t)NN * C;
  // a_t/b_t live inside d_out (2 bf16 planes == fp32 output bytes); K4 overwrites last.
  ushort_t* a_t = (ushort_t*)d_out;
  ushort_t* b_t = a_t + (size_t)NN * C;
  float* outp = (float*)d_out;

  k1_ln<<<NN / 4, 256, 0, stream>>>(z, w_in, b_in, zn);
  k0_cvt<<<384, 256, 0, stream>>>(zw, Wp, Wg, Wgate, zwb, Wall);
  k2_proj<<<4608, 256, 0, stream>>>(zn, Wall, bp, bg, mask, a_t, b_t);
  k3_tri<<<4608, 256, 0, stream>>>(a_t, b_t, x_t);
  k4_out<<<9216, 256, 0, stream>>>(x_t, zn, zwb, Wall + (size_t)512 * C,
                                   w_out, b_out, zb, bgate, outp);
}